// Round 7
// baseline (350.134 us; speedup 1.0000x reference)
//
#include <hip/hip_runtime.h>
#include <hip/hip_fp16.h>

// Problem constants (fixed by the reference file)
#define NN 50000     // nodes
#define NE 800000    // edges
#define HD 64        // feature dim (in and hidden)
#define NG 512       // graphs
#define NBK 196      // buckets: col >> 8, max 49999>>8 = 195
#define NBL 196      // edge blocks of 4096: ceil(NE/4096)
#define M_CNT (NBK * NBL)       // 38416 counts
#define NBS 151                 // scan blocks: ceil(M_CNT/256)
#define GEMM_BLOCKS 3125        // NN/16

// Feature arrays use PLANE layout: [plane][node][32ch], plane p = ch>>5.
// Each plane is 3.2 MB -> fits per-XCD 4 MiB L2 during a gather pass.

// ---------------------------------------------------------------------------
__global__ void zero_kernel(int* __restrict__ p, int n) {
    int i = blockIdx.x * blockDim.x + threadIdx.x;
    if (i < n) p[i] = 0;
}

// ---------------------------------------------------------------------------
// Pass A: per-(block,bucket) edge counts via LDS histogram (no global atomics)
// + graph node counts via sorted-batch boundary detection (atomic-free).
__global__ __launch_bounds__(256) void bucket_count(const int* __restrict__ col,
                                                    const int* __restrict__ batch,
                                                    int* __restrict__ counts,
                                                    int* __restrict__ beg,
                                                    int* __restrict__ endx) {
    __shared__ int hist[256];
    int tid = threadIdx.x, blk = blockIdx.x;
    hist[tid] = 0;
    __syncthreads();
    int base = blk * 4096;
#pragma unroll
    for (int k = 0; k < 16; ++k) {
        int e = base + k * 256 + tid;
        if (e < NE) atomicAdd(&hist[col[e] >> 8], 1);
    }
    // batch boundaries (batch is sorted); grid covers 50176 >= NN threads
    int t = blk * 256 + tid;
    if (t < NN) {
        int g = batch[t];
        if (t == 0 || batch[t - 1] != g) beg[g] = t;
        if (t == NN - 1 || batch[t + 1] != g) endx[g] = t + 1;
    }
    __syncthreads();
    if (tid < NBK) counts[tid * NBL + blk] = hist[tid];  // bucket-major
}

// ---- 3-stage exclusive scan over counts[M_CNT] ----------------------------
__global__ __launch_bounds__(256) void block_reduce(const int* __restrict__ src,
                                                    int* __restrict__ bsum) {
    __shared__ int ws[4];
    int tid = threadIdx.x, lane = tid & 63, wid = tid >> 6;
    int i = blockIdx.x * 256 + tid;
    int v = (i < M_CNT) ? src[i] : 0;
#pragma unroll
    for (int off = 32; off > 0; off >>= 1) v += __shfl_down(v, off, 64);
    if (lane == 0) ws[wid] = v;
    __syncthreads();
    if (tid == 0) bsum[blockIdx.x] = ws[0] + ws[1] + ws[2] + ws[3];
}

__global__ __launch_bounds__(64) void scan_bsum(int* __restrict__ bsum) {
    int lane = threadIdx.x;
    int carry = 0;
    for (int base = 0; base < NBS; base += 64) {
        int i = base + lane;
        int v = (i < NBS) ? bsum[i] : 0;
        int inc = v;
#pragma unroll
        for (int off = 1; off < 64; off <<= 1) {
            int t = __shfl_up(inc, off, 64);
            if (lane >= off) inc += t;
        }
        if (i < NBS) bsum[i] = carry + inc - v;  // exclusive
        carry += __shfl(inc, 63, 64);
    }
}

__global__ __launch_bounds__(256) void block_scan(const int* __restrict__ src,
                                                  const int* __restrict__ bsum,
                                                  int* __restrict__ dst) {
    __shared__ int ws[4];
    int tid = threadIdx.x, lane = tid & 63, wid = tid >> 6;
    int i = blockIdx.x * 256 + tid;
    int v = (i < M_CNT) ? src[i] : 0;
    int inc = v;
#pragma unroll
    for (int off = 1; off < 64; off <<= 1) {
        int t = __shfl_up(inc, off, 64);
        if (lane >= off) inc += t;
    }
    if (lane == 63) ws[wid] = inc;
    __syncthreads();
    int woff = 0;
    for (int k = 0; k < wid; ++k) woff += ws[k];
    if (i < M_CNT) dst[i] = bsum[blockIdx.x] + woff + inc - v;
}

// ---------------------------------------------------------------------------
// Fused: blocks [0,GEMM_BLOCKS) do h16 = x @ W1 (fp32 in, fp16 plane out);
// blocks [GEMM_BLOCKS, +NBL) scatter edges into bucket-ordered packed[].
__global__ __launch_bounds__(256) void gemm1_scatter(const float* __restrict__ x,
                                                     const float* __restrict__ W1,
                                                     __half* __restrict__ h16,
                                                     const int* __restrict__ row,
                                                     const int* __restrict__ col,
                                                     const int* __restrict__ counts_ex,
                                                     unsigned* __restrict__ packed) {
    if (blockIdx.x < GEMM_BLOCKS) {
        __shared__ float Ws[64][64];   // 16 KB
        __shared__ float Is[16][64];   // 4 KB
        int t = threadIdx.x;
        for (int i = t; i < 64 * 64; i += 256) Ws[i >> 6][i & 63] = W1[i];
        int row0 = blockIdx.x * 16;
        for (int i = t; i < 16 * 64; i += 256)
            Is[i >> 6][i & 63] = x[(row0 + (i >> 6)) * HD + (i & 63)];
        __syncthreads();
        int c = t & 63, r4 = t >> 6;
        float a0 = 0.f, a1 = 0.f, a2 = 0.f, a3 = 0.f;
#pragma unroll
        for (int k = 0; k < 64; ++k) {
            float w = Ws[k][c];
            a0 += Is[r4 + 0][k] * w;
            a1 += Is[r4 + 4][k] * w;
            a2 += Is[r4 + 8][k] * w;
            a3 += Is[r4 + 12][k] * w;
        }
        size_t pb = (size_t)(c >> 5) * NN * 32 + (c & 31);  // plane layout
        h16[pb + (size_t)(row0 + r4 + 0) * 32] = __float2half(a0);
        h16[pb + (size_t)(row0 + r4 + 4) * 32] = __float2half(a1);
        h16[pb + (size_t)(row0 + r4 + 8) * 32] = __float2half(a2);
        h16[pb + (size_t)(row0 + r4 + 12) * 32] = __float2half(a3);
    } else {
        __shared__ int cur[256];
        int tid = threadIdx.x, blk = blockIdx.x - GEMM_BLOCKS;
        cur[tid] = 0;
        __syncthreads();
        int base = blk * 4096;
#pragma unroll
        for (int k = 0; k < 16; ++k) {
            int e = base + k * 256 + tid;
            if (e < NE) {
                int c = col[e], r = row[e];
                int b = c >> 8;
                int lpos = atomicAdd(&cur[b], 1);
                int pos = counts_ex[b * NBL + blk] + lpos;
                packed[pos] = (unsigned)r | ((unsigned)(c & 255) << 16);
            }
        }
    }
}

// ---------------------------------------------------------------------------
// D1: per-bucket LDS histogram + scan -> rowptr, dinv (no global atomics)
__global__ __launch_bounds__(256) void csr_rowptr(const unsigned* __restrict__ packed,
                                                  const int* __restrict__ counts_ex,
                                                  int* __restrict__ rowptr,
                                                  float* __restrict__ dinv) {
    __shared__ int hist[256];
    __shared__ int ws[4];
    int bkt = blockIdx.x, tid = threadIdx.x;
    int s = counts_ex[bkt * NBL];
    int e = (bkt == NBK - 1) ? NE : counts_ex[(bkt + 1) * NBL];
    hist[tid] = 0;
    __syncthreads();
    for (int j = s + tid; j < e; j += 256)
        atomicAdd(&hist[(packed[j] >> 16) & 255], 1);
    __syncthreads();
    int lane = tid & 63, wid = tid >> 6;
    int v = hist[tid], inc = v;
#pragma unroll
    for (int off = 1; off < 64; off <<= 1) {
        int t = __shfl_up(inc, off, 64);
        if (lane >= off) inc += t;
    }
    if (lane == 63) ws[wid] = inc;
    __syncthreads();
    int woff = 0;
    for (int k = 0; k < wid; ++k) woff += ws[k];
    int node = bkt * 256 + tid;
    if (node < NN) {
        rowptr[node] = s + woff + inc - v;      // exclusive
        dinv[node] = rsqrtf((float)(v + 1));    // +1 self-loop
    }
    if (bkt == 0 && tid == 0) rowptr[NN] = NE;
}

// D2: fill CSR (src, weight) via LDS cursors; rowptr/dinv reads are L2-hot
__global__ __launch_bounds__(256) void csr_fill(const unsigned* __restrict__ packed,
                                                const int* __restrict__ counts_ex,
                                                const int* __restrict__ rowptr,
                                                const float* __restrict__ dinv,
                                                int2* __restrict__ ew) {
    __shared__ int cur[256];
    int bkt = blockIdx.x, tid = threadIdx.x;
    int s = counts_ex[bkt * NBL];
    int e = (bkt == NBK - 1) ? NE : counts_ex[(bkt + 1) * NBL];
    cur[tid] = 0;
    __syncthreads();
    for (int j = s + tid; j < e; j += 256) {
        unsigned p = packed[j];
        int r = p & 0xFFFF;
        int lc = (p >> 16) & 255;
        int c = (bkt << 8) | lc;
        int slot = rowptr[c] + atomicAdd(&cur[lc], 1);
        float w = dinv[r] * dinv[c];
        ew[slot] = make_int2(r, __float_as_int(w));
    }
}

// ---------------------------------------------------------------------------
// h16 = relu(in16) @ W   (layers 2,3); in/out in plane layout
__global__ __launch_bounds__(256) void gemm64_f16(const __half* __restrict__ in,
                                                  const float* __restrict__ W,
                                                  __half* __restrict__ out) {
    __shared__ float Ws[64][64];
    __shared__ float Is[16][64];
    int t = threadIdx.x;
    for (int i = t; i < 64 * 64; i += 256) Ws[i >> 6][i & 63] = W[i];
    int row0 = blockIdx.x * 16;
    const __half2* p0 = (const __half2*)(in + (size_t)row0 * 32);
    const __half2* p1 = (const __half2*)(in + ((size_t)NN + row0) * 32);
    {
        int i = t;  // 256 threads cover 256 half2 per plane exactly
        int r = i >> 4, cc = (i & 15) * 2;
        float2 v = __half22float2(p0[i]);
        Is[r][cc]     = fmaxf(v.x, 0.f);
        Is[r][cc + 1] = fmaxf(v.y, 0.f);
        float2 w = __half22float2(p1[i]);
        Is[r][32 + cc]     = fmaxf(w.x, 0.f);
        Is[r][32 + cc + 1] = fmaxf(w.y, 0.f);
    }
    __syncthreads();
    int c = t & 63, r4 = t >> 6;
    float a0 = 0.f, a1 = 0.f, a2 = 0.f, a3 = 0.f;
#pragma unroll
    for (int k = 0; k < 64; ++k) {
        float w = Ws[k][c];
        a0 += Is[r4 + 0][k] * w;
        a1 += Is[r4 + 4][k] * w;
        a2 += Is[r4 + 8][k] * w;
        a3 += Is[r4 + 12][k] * w;
    }
    size_t pb = (size_t)(c >> 5) * NN * 32 + (c & 31);
    out[pb + (size_t)(row0 + r4 + 0) * 32] = __float2half(a0);
    out[pb + (size_t)(row0 + r4 + 4) * 32] = __float2half(a1);
    out[pb + (size_t)(row0 + r4 + 8) * 32] = __float2half(a2);
    out[pb + (size_t)(row0 + r4 + 12) * 32] = __float2half(a3);
}

// ---------------------------------------------------------------------------
// Plane gather: ONE node per wave, one 3.2 MB plane per dispatch (L2-resident).
// 4 edge-stream groups of 16 lanes; 16 lanes x half2 = 64 B plane row.
// ew via non-temporal loads, output via non-temporal stores (protect L2).
template <bool POOL>
__global__ __launch_bounds__(256) void gather_plane(const __half* __restrict__ hp,
                                                    const int* __restrict__ rowptr,
                                                    const int2* __restrict__ ew,
                                                    const float* __restrict__ dinv,
                                                    const float* __restrict__ bp,
                                                    __half* __restrict__ outp,
                                                    const int* __restrict__ batch,
                                                    float* __restrict__ pooled,
                                                    int poff) {
    int tid = threadIdx.x, lane = tid & 63, wid = tid >> 6;
    int g = lane >> 4, c = lane & 15;         // edge-stream group, half2 channel
    int node = blockIdx.x * 4 + wid;          // NN = 12500*4 exact
    const __half2* hv = (const __half2*)hp;   // [NN][16]
    int s = rowptr[node], e = rowptr[node + 1];
    float2 acc = {0.f, 0.f};
    if (g == 0) {  // self-loop + bias in group 0 only (groups summed later)
        float di = dinv[node], dd = di * di;
        float2 self = __half22float2(hv[node * 16 + c]);
        float2 bb = ((const float2*)bp)[c];
        acc.x = dd * self.x + bb.x;
        acc.y = dd * self.y + bb.y;
    }
    // stream g: edges s+g, s+g+4, ...; process pairs (j, j+4)
    int j = s + g;
    for (; j + 4 < e; j += 8) {
        long long q0 = __builtin_nontemporal_load((const long long*)(ew + j));
        long long q1 = __builtin_nontemporal_load((const long long*)(ew + j + 4));
        int s0 = (int)q0, s1 = (int)q1;
        float w0 = __int_as_float((int)(q0 >> 32));
        float w1 = __int_as_float((int)(q1 >> 32));
        float2 f0 = __half22float2(hv[s0 * 16 + c]);
        float2 f1 = __half22float2(hv[s1 * 16 + c]);
        acc.x += w0 * f0.x + w1 * f1.x;
        acc.y += w0 * f0.y + w1 * f1.y;
    }
    if (j < e) {
        long long q = __builtin_nontemporal_load((const long long*)(ew + j));
        float w = __int_as_float((int)(q >> 32));
        float2 f = __half22float2(hv[((int)q) * 16 + c]);
        acc.x += w * f.x;
        acc.y += w * f.y;
    }
    // combine 4 group partials (lanes with equal (lane&15) hold same channels)
    acc.x += __shfl_xor(acc.x, 16, 64);
    acc.y += __shfl_xor(acc.y, 16, 64);
    acc.x += __shfl_xor(acc.x, 32, 64);
    acc.y += __shfl_xor(acc.y, 32, 64);
    if (g == 0) {
        if (POOL) {
            int gr = batch[node];
            atomicAdd(&pooled[gr * HD + poff + 2 * c], acc.x);
            atomicAdd(&pooled[gr * HD + poff + 2 * c + 1], acc.y);
        } else {
            union { __half2 h; unsigned u; } cv;
            cv.h = __floats2half2_rn(acc.x, acc.y);
            __builtin_nontemporal_store(cv.u, (unsigned*)outp + node * 16 + c);
        }
    }
}

// out[g] = (pooled[g,:]/max(cnt,1)) . lin_W + lin_b   — one wave per graph
__global__ __launch_bounds__(64) void final_kernel(const float* __restrict__ pooled,
                                                   const int* __restrict__ beg,
                                                   const int* __restrict__ endx,
                                                   const float* __restrict__ lin_W,
                                                   const float* __restrict__ lin_b,
                                                   float* __restrict__ out) {
    int g = blockIdx.x, d = threadIdx.x;
    float cnt = (float)(endx[g] - beg[g]);
    float v = pooled[g * HD + d] / fmaxf(cnt, 1.f) * lin_W[d];
#pragma unroll
    for (int off = 32; off > 0; off >>= 1) v += __shfl_down(v, off, 64);
    if (d == 0) out[g] = v + lin_b[0];
}

// ---------------------------------------------------------------------------
extern "C" void kernel_launch(void* const* d_in, const int* in_sizes, int n_in,
                              void* d_out, int out_size, void* d_ws, size_t ws_size,
                              hipStream_t stream) {
    const float* x     = (const float*)d_in[0];
    const float* W1    = (const float*)d_in[1];
    const float* b1    = (const float*)d_in[2];
    const float* W2    = (const float*)d_in[3];
    const float* b2    = (const float*)d_in[4];
    const float* W3    = (const float*)d_in[5];
    const float* b3    = (const float*)d_in[6];
    const float* lin_W = (const float*)d_in[7];
    const float* lin_b = (const float*)d_in[8];
    const int* edge_index = (const int*)d_in[9];   // [2, NE]: row then col
    const int* batch      = (const int*)d_in[10];
    const int* row = edge_index;
    const int* col = edge_index + NE;
    float* out = (float*)d_out;

    // workspace layout (4B units):
    // [h16 NN*HD half][A16 NN*HD half][ew NE int2][packed NE uint]
    // [counts M][counts_ex M][rowptr NN+2][dinv NN][bsum 256]
    // [pooled NG*HD][beg NG][endx NG]
    __half*   h16       = (__half*)d_ws;
    __half*   A16       = h16 + (size_t)NN * HD;
    int2*     ew        = (int2*)(A16 + (size_t)NN * HD);
    unsigned* packed    = (unsigned*)(ew + NE);
    int*      counts    = (int*)(packed + NE);
    int*      counts_ex = counts + M_CNT;
    int*      rowptr    = counts_ex + M_CNT;
    float*    dinv      = (float*)(rowptr + NN + 2);
    int*      bsum      = (int*)(dinv + NN);
    float*    pooled    = (float*)(bsum + 256);
    int*      beg       = (int*)(pooled + NG * HD);
    int*      endx      = beg + NG;

    const size_t PL = (size_t)NN * 32;  // halfs per plane

    // zero pooled|beg|endx (contiguous)
    const int ZN = NG * HD + 2 * NG;
    zero_kernel<<<(ZN + 255) / 256, 256, 0, stream>>>((int*)pooled, ZN);

    // CSR build: count -> scan -> (scatter fused w/ gemm1) -> rowptr -> fill
    bucket_count<<<NBL, 256, 0, stream>>>(col, batch, counts, beg, endx);
    block_reduce<<<NBS, 256, 0, stream>>>(counts, bsum);
    scan_bsum<<<1, 64, 0, stream>>>(bsum);
    block_scan<<<NBS, 256, 0, stream>>>(counts, bsum, counts_ex);
    gemm1_scatter<<<GEMM_BLOCKS + NBL, 256, 0, stream>>>(x, W1, h16, row, col,
                                                         counts_ex, packed);
    csr_rowptr<<<NBK, 256, 0, stream>>>(packed, counts_ex, rowptr, dinv);
    csr_fill<<<NBK, 256, 0, stream>>>(packed, counts_ex, rowptr, dinv, ew);

    const int GB = NN / 4;  // gather blocks: 4 nodes (waves) each

    // Layer 1 aggregate: h16 -> A16 (two plane passes)
    gather_plane<false><<<GB, 256, 0, stream>>>(h16, rowptr, ew, dinv, b1, A16,
                                                batch, pooled, 0);
    gather_plane<false><<<GB, 256, 0, stream>>>(h16 + PL, rowptr, ew, dinv,
                                                b1 + 32, A16 + PL, batch, pooled, 32);
    // Layer 2: relu(A16) -> h16 -> A16
    gemm64_f16<<<GEMM_BLOCKS, 256, 0, stream>>>(A16, W2, h16);
    gather_plane<false><<<GB, 256, 0, stream>>>(h16, rowptr, ew, dinv, b2, A16,
                                                batch, pooled, 0);
    gather_plane<false><<<GB, 256, 0, stream>>>(h16 + PL, rowptr, ew, dinv,
                                                b2 + 32, A16 + PL, batch, pooled, 32);
    // Layer 3: relu(A16) -> h16 -> pooled (fused)
    gemm64_f16<<<GEMM_BLOCKS, 256, 0, stream>>>(A16, W3, h16);
    gather_plane<true><<<GB, 256, 0, stream>>>(h16, rowptr, ew, dinv, b3, nullptr,
                                               batch, pooled, 0);
    gather_plane<true><<<GB, 256, 0, stream>>>(h16 + PL, rowptr, ew, dinv,
                                               b3 + 32, nullptr, batch, pooled, 32);

    final_kernel<<<NG, 64, 0, stream>>>(pooled, beg, endx, lin_W, lin_b, out);
}

// Round 11
// 271.264 us; speedup vs baseline: 1.2908x; 1.2908x over previous
//
#include <hip/hip_runtime.h>
#include <hip/hip_fp16.h>

// Problem constants (fixed by the reference file)
#define NN 50000     // nodes
#define NE 800000    // edges
#define HD 64        // feature dim (in and hidden)
#define NG 512       // graphs
#define NBK 196      // buckets: col >> 8, max 49999>>8 = 195
#define NBL 196      // edge blocks of 4096: ceil(NE/4096)
#define M_CNT (NBK * NBL)       // 38416 counts
#define NBS 151                 // scan blocks: ceil(M_CNT/256)
#define GEMM_BLOCKS 3125        // NN/16

// Math: out[c] = dinv[c]*(sum_src dinv[src]*h[src]) + dinv[c]^2*h[c] + b.
// Edge stream stores ONLY src (4 B/edge, value <= 0xFFFF); w = dinv[src] is
// gathered once per lane per 64-edge chunk and broadcast via __shfl.
// CRITICAL (R8/R10 bug): every __shfl must execute with ALL 64 lanes active.
// ds_bpermute returns 0 from exec-masked-off source lanes, so divergent loop
// trip counts between the two half-waves silently drop edges. All loop bounds
// below are wave-uniform; the tail is a fixed 4-iteration predicated loop.

// ---------------------------------------------------------------------------
__global__ void zero_kernel(int* __restrict__ p, int n) {
    int i = blockIdx.x * blockDim.x + threadIdx.x;
    if (i < n) p[i] = 0;
}

// ---------------------------------------------------------------------------
// Pass A: per-(block,bucket) edge counts via LDS histogram (no global atomics)
// + graph node counts via sorted-batch boundary detection (atomic-free).
__global__ __launch_bounds__(256) void bucket_count(const int* __restrict__ col,
                                                    const int* __restrict__ batch,
                                                    int* __restrict__ counts,
                                                    int* __restrict__ beg,
                                                    int* __restrict__ endx) {
    __shared__ int hist[256];
    int tid = threadIdx.x, blk = blockIdx.x;
    hist[tid] = 0;
    __syncthreads();
    int base = blk * 4096;
#pragma unroll
    for (int k = 0; k < 16; ++k) {
        int e = base + k * 256 + tid;
        if (e < NE) atomicAdd(&hist[col[e] >> 8], 1);
    }
    // batch boundaries (batch is sorted); grid covers 50176 >= NN threads
    int t = blk * 256 + tid;
    if (t < NN) {
        int g = batch[t];
        if (t == 0 || batch[t - 1] != g) beg[g] = t;
        if (t == NN - 1 || batch[t + 1] != g) endx[g] = t + 1;
    }
    __syncthreads();
    if (tid < NBK) counts[tid * NBL + blk] = hist[tid];  // bucket-major
}

// ---- 3-stage exclusive scan over counts[M_CNT] ----------------------------
__global__ __launch_bounds__(256) void block_reduce(const int* __restrict__ src,
                                                    int* __restrict__ bsum) {
    __shared__ int ws[4];
    int tid = threadIdx.x, lane = tid & 63, wid = tid >> 6;
    int i = blockIdx.x * 256 + tid;
    int v = (i < M_CNT) ? src[i] : 0;
#pragma unroll
    for (int off = 32; off > 0; off >>= 1) v += __shfl_down(v, off, 64);
    if (lane == 0) ws[wid] = v;
    __syncthreads();
    if (tid == 0) bsum[blockIdx.x] = ws[0] + ws[1] + ws[2] + ws[3];
}

__global__ __launch_bounds__(64) void scan_bsum(int* __restrict__ bsum) {
    int lane = threadIdx.x;
    int carry = 0;
    for (int base = 0; base < NBS; base += 64) {
        int i = base + lane;
        int v = (i < NBS) ? bsum[i] : 0;
        int inc = v;
#pragma unroll
        for (int off = 1; off < 64; off <<= 1) {
            int t = __shfl_up(inc, off, 64);
            if (lane >= off) inc += t;
        }
        if (i < NBS) bsum[i] = carry + inc - v;  // exclusive
        carry += __shfl(inc, 63, 64);
    }
}

__global__ __launch_bounds__(256) void block_scan(const int* __restrict__ src,
                                                  const int* __restrict__ bsum,
                                                  int* __restrict__ dst) {
    __shared__ int ws[4];
    int tid = threadIdx.x, lane = tid & 63, wid = tid >> 6;
    int i = blockIdx.x * 256 + tid;
    int v = (i < M_CNT) ? src[i] : 0;
    int inc = v;
#pragma unroll
    for (int off = 1; off < 64; off <<= 1) {
        int t = __shfl_up(inc, off, 64);
        if (lane >= off) inc += t;
    }
    if (lane == 63) ws[wid] = inc;
    __syncthreads();
    int woff = 0;
    for (int k = 0; k < wid; ++k) woff += ws[k];
    if (i < M_CNT) dst[i] = bsum[blockIdx.x] + woff + inc - v;
}

// ---------------------------------------------------------------------------
// Fused: blocks [0,GEMM_BLOCKS) do h16 = x @ W1 (fp32 in, fp16 out);
// blocks [GEMM_BLOCKS, +NBL) scatter edges into bucket-ordered packed[].
__global__ __launch_bounds__(256) void gemm1_scatter(const float* __restrict__ x,
                                                     const float* __restrict__ W1,
                                                     __half* __restrict__ h16,
                                                     const int* __restrict__ row,
                                                     const int* __restrict__ col,
                                                     const int* __restrict__ counts_ex,
                                                     unsigned* __restrict__ packed) {
    if (blockIdx.x < GEMM_BLOCKS) {
        __shared__ float Ws[64][64];   // 16 KB
        __shared__ float Is[16][64];   // 4 KB
        int t = threadIdx.x;
        for (int i = t; i < 64 * 64; i += 256) Ws[i >> 6][i & 63] = W1[i];
        int row0 = blockIdx.x * 16;
        for (int i = t; i < 16 * 64; i += 256)
            Is[i >> 6][i & 63] = x[(row0 + (i >> 6)) * HD + (i & 63)];
        __syncthreads();
        int c = t & 63, r4 = t >> 6;
        float a0 = 0.f, a1 = 0.f, a2 = 0.f, a3 = 0.f;
#pragma unroll
        for (int k = 0; k < 64; ++k) {
            float w = Ws[k][c];
            a0 += Is[r4 + 0][k] * w;
            a1 += Is[r4 + 4][k] * w;
            a2 += Is[r4 + 8][k] * w;
            a3 += Is[r4 + 12][k] * w;
        }
        h16[(row0 + r4 + 0) * HD + c] = __float2half(a0);
        h16[(row0 + r4 + 4) * HD + c] = __float2half(a1);
        h16[(row0 + r4 + 8) * HD + c] = __float2half(a2);
        h16[(row0 + r4 + 12) * HD + c] = __float2half(a3);
    } else {
        __shared__ int cur[256];
        int tid = threadIdx.x, blk = blockIdx.x - GEMM_BLOCKS;
        cur[tid] = 0;
        __syncthreads();
        int base = blk * 4096;
#pragma unroll
        for (int k = 0; k < 16; ++k) {
            int e = base + k * 256 + tid;
            if (e < NE) {
                int c = col[e], r = row[e];
                int b = c >> 8;
                int lpos = atomicAdd(&cur[b], 1);
                int pos = counts_ex[b * NBL + blk] + lpos;
                packed[pos] = (unsigned)r | ((unsigned)(c & 255) << 16);
            }
        }
    }
}

// ---------------------------------------------------------------------------
// D1: per-bucket LDS histogram + scan -> rowptr, dinv (no global atomics)
__global__ __launch_bounds__(256) void csr_rowptr(const unsigned* __restrict__ packed,
                                                  const int* __restrict__ counts_ex,
                                                  int* __restrict__ rowptr,
                                                  float* __restrict__ dinv) {
    __shared__ int hist[256];
    __shared__ int ws[4];
    int bkt = blockIdx.x, tid = threadIdx.x;
    int s = counts_ex[bkt * NBL];
    int e = (bkt == NBK - 1) ? NE : counts_ex[(bkt + 1) * NBL];
    hist[tid] = 0;
    __syncthreads();
    for (int j = s + tid; j < e; j += 256)
        atomicAdd(&hist[(packed[j] >> 16) & 255], 1);
    __syncthreads();
    int lane = tid & 63, wid = tid >> 6;
    int v = hist[tid], inc = v;
#pragma unroll
    for (int off = 1; off < 64; off <<= 1) {
        int t = __shfl_up(inc, off, 64);
        if (lane >= off) inc += t;
    }
    if (lane == 63) ws[wid] = inc;
    __syncthreads();
    int woff = 0;
    for (int k = 0; k < wid; ++k) woff += ws[k];
    int node = bkt * 256 + tid;
    if (node < NN) {
        rowptr[node] = s + woff + inc - v;      // exclusive
        dinv[node] = rsqrtf((float)(v + 1));    // +1 self-loop
    }
    if (bkt == 0 && tid == 0) rowptr[NN] = NE;
}

// D2: fill CSR src list via LDS cursors (4 B/edge, no weights)
__global__ __launch_bounds__(256) void csr_fill(const unsigned* __restrict__ packed,
                                                const int* __restrict__ counts_ex,
                                                const int* __restrict__ rowptr,
                                                int* __restrict__ esrc) {
    __shared__ int cur[256];
    int bkt = blockIdx.x, tid = threadIdx.x;
    int s = counts_ex[bkt * NBL];
    int e = (bkt == NBK - 1) ? NE : counts_ex[(bkt + 1) * NBL];
    cur[tid] = 0;
    __syncthreads();
    for (int j = s + tid; j < e; j += 256) {
        unsigned p = packed[j];
        int lc = (p >> 16) & 255;
        int slot = rowptr[(bkt << 8) | lc] + atomicAdd(&cur[lc], 1);
        esrc[slot] = (int)(p & 0xFFFF);   // NN < 65536, src fits 16 bits
    }
}

// ---------------------------------------------------------------------------
// h16 = relu(in16) @ W   (layers 2,3)
__global__ __launch_bounds__(256) void gemm64_f16(const __half* __restrict__ in,
                                                  const float* __restrict__ W,
                                                  __half* __restrict__ out) {
    __shared__ float Ws[64][64];
    __shared__ float Is[16][64];
    int t = threadIdx.x;
    for (int i = t; i < 64 * 64; i += 256) Ws[i >> 6][i & 63] = W[i];
    int row0 = blockIdx.x * 16;
    const __half2* in2 = (const __half2*)(in + (size_t)row0 * HD);
    for (int i = t; i < 16 * 32; i += 256) {
        float2 v = __half22float2(in2[i]);
        int r = i >> 5, c2 = (i & 31) * 2;
        Is[r][c2]     = fmaxf(v.x, 0.f);
        Is[r][c2 + 1] = fmaxf(v.y, 0.f);
    }
    __syncthreads();
    int c = t & 63, r4 = t >> 6;
    float a0 = 0.f, a1 = 0.f, a2 = 0.f, a3 = 0.f;
#pragma unroll
    for (int k = 0; k < 64; ++k) {
        float w = Ws[k][c];
        a0 += Is[r4 + 0][k] * w;
        a1 += Is[r4 + 4][k] * w;
        a2 += Is[r4 + 8][k] * w;
        a3 += Is[r4 + 12][k] * w;
    }
    out[(row0 + r4 + 0) * HD + c] = __float2half(a0);
    out[(row0 + r4 + 4) * HD + c] = __float2half(a1);
    out[(row0 + r4 + 8) * HD + c] = __float2half(a2);
    out[(row0 + r4 + 12) * HD + c] = __float2half(a3);
}

// ---------------------------------------------------------------------------
// Src-only CSR gather: ONE node per wave. Per 64-edge chunk, one coalesced
// load of src ids + one gather of w=dinv[src]; per-edge (src,w) broadcast via
// __shfl. ALL loop bounds are wave-uniform: main loop runs nk>>3 iterations
// (both halves fully valid), tail is a FIXED 4-iteration predicated loop —
// every __shfl executes with all 64 lanes active (see header comment).
template <bool POOL>
__global__ __launch_bounds__(256) void gather_s(const __half* __restrict__ hp,
                                                const int* __restrict__ rowptr,
                                                const int* __restrict__ esrc,
                                                const float* __restrict__ dinv,
                                                const float* __restrict__ b,
                                                __half* __restrict__ out16,
                                                const int* __restrict__ batch,
                                                float* __restrict__ pooled) {
    int tid = threadIdx.x, lane = tid & 63, wid = tid >> 6;
    int hh = lane >> 5, c = lane & 31;          // half-wave id, half2 channel
    int node = blockIdx.x * 4 + wid;            // NN = 12500*4 exact
    const __half2* hv = (const __half2*)hp;
    int s = rowptr[node], e = rowptr[node + 1];
    int deg = e - s;
    float2 acc = {0.f, 0.f};
    for (int k = 0; k < deg; k += 64) {         // deg wave-uniform
        // mask &0xFFFF: pad/overhang entries may be poison; keep the index
        // small so the speculative dinv/hv reads stay inside the workspace.
        int my = esrc[s + k + lane] & 0xFFFF;   // coalesced; esrc padded +64
        float myw = dinv[my];                   // L2-hot 200 KB gather
        int nk = min(deg - k, 64);              // wave-uniform
        int nmain = nk >> 3;                    // full 8-edge groups, uniform
        for (int j = 0; j < nmain; ++j) {
            int t = j * 8 + hh;                 // t..t+6 all < nk for both hh
            int s0 = __shfl(my, t, 64);
            int s1 = __shfl(my, t + 2, 64);
            int s2 = __shfl(my, t + 4, 64);
            int s3 = __shfl(my, t + 6, 64);
            float w0 = __shfl(myw, t, 64);
            float w1 = __shfl(myw, t + 2, 64);
            float w2 = __shfl(myw, t + 4, 64);
            float w3 = __shfl(myw, t + 6, 64);
            float2 f0 = __half22float2(hv[s0 * 32 + c]);
            float2 f1 = __half22float2(hv[s1 * 32 + c]);
            float2 f2 = __half22float2(hv[s2 * 32 + c]);
            float2 f3 = __half22float2(hv[s3 * 32 + c]);
            acc.x += w0 * f0.x + w1 * f1.x + w2 * f2.x + w3 * f3.x;
            acc.y += w0 * f0.y + w1 * f1.y + w2 * f2.y + w3 * f3.y;
        }
        // fixed 4-iteration predicated tail (uniform; covers t in [nk&~7, nk))
        int tbase = (nk & ~7) + hh;
#pragma unroll
        for (int u = 0; u < 4; ++u) {
            int t = tbase + 2 * u;
            int sl = __shfl(my, t & 63, 64);    // all lanes active; lane<64
            float w = __shfl(myw, t & 63, 64);
            float wm = (t < nk) ? w : 0.f;      // drop out-of-range edges
            float2 f = __half22float2(hv[sl * 32 + c]);
            acc.x += wm * f.x;
            acc.y += wm * f.y;
        }
    }
    // combine the two half-wave partials (lane L ^ 32 holds same channels)
    acc.x += __shfl_xor(acc.x, 32, 64);
    acc.y += __shfl_xor(acc.y, 32, 64);
    if (hh == 0) {
        float di = dinv[node];
        float2 self = __half22float2(hv[node * 32 + c]);
        float2 bb = ((const float2*)b)[c];
        float vx = di * acc.x + di * di * self.x + bb.x;
        float vy = di * acc.y + di * di * self.y + bb.y;
        if (POOL) {
            int g = batch[node];
            atomicAdd(&pooled[g * HD + 2 * c], vx);
            atomicAdd(&pooled[g * HD + 2 * c + 1], vy);
        } else {
            ((__half2*)out16)[node * 32 + c] = __floats2half2_rn(vx, vy);
        }
    }
}

// out[g] = (pooled[g,:]/max(cnt,1)) . lin_W + lin_b   — one wave per graph
__global__ __launch_bounds__(64) void final_kernel(const float* __restrict__ pooled,
                                                   const int* __restrict__ beg,
                                                   const int* __restrict__ endx,
                                                   const float* __restrict__ lin_W,
                                                   const float* __restrict__ lin_b,
                                                   float* __restrict__ out) {
    int g = blockIdx.x, d = threadIdx.x;
    float cnt = (float)(endx[g] - beg[g]);
    float v = pooled[g * HD + d] / fmaxf(cnt, 1.f) * lin_W[d];
#pragma unroll
    for (int off = 32; off > 0; off >>= 1) v += __shfl_down(v, off, 64);
    if (d == 0) out[g] = v + lin_b[0];
}

// ---------------------------------------------------------------------------
extern "C" void kernel_launch(void* const* d_in, const int* in_sizes, int n_in,
                              void* d_out, int out_size, void* d_ws, size_t ws_size,
                              hipStream_t stream) {
    const float* x     = (const float*)d_in[0];
    const float* W1    = (const float*)d_in[1];
    const float* b1    = (const float*)d_in[2];
    const float* W2    = (const float*)d_in[3];
    const float* b2    = (const float*)d_in[4];
    const float* W3    = (const float*)d_in[5];
    const float* b3    = (const float*)d_in[6];
    const float* lin_W = (const float*)d_in[7];
    const float* lin_b = (const float*)d_in[8];
    const int* edge_index = (const int*)d_in[9];   // [2, NE]: row then col
    const int* batch      = (const int*)d_in[10];
    const int* row = edge_index;
    const int* col = edge_index + NE;
    float* out = (float*)d_out;

    // workspace layout (4B units):
    // [h16 NN*HD half][A16 NN*HD half][esrc NE+64][packed NE]
    // [counts M][counts_ex M][rowptr NN+2][dinv NN][bsum 256]
    // [pooled NG*HD][beg NG][endx NG]
    __half*   h16       = (__half*)d_ws;
    __half*   A16       = h16 + (size_t)NN * HD;
    int*      esrc      = (int*)(A16 + (size_t)NN * HD);
    unsigned* packed    = (unsigned*)(esrc + NE + 64);
    int*      counts    = (int*)(packed + NE);
    int*      counts_ex = counts + M_CNT;
    int*      rowptr    = counts_ex + M_CNT;
    float*    dinv      = (float*)(rowptr + NN + 2);
    int*      bsum      = (int*)(dinv + NN);
    float*    pooled    = (float*)(bsum + 256);
    int*      beg       = (int*)(pooled + NG * HD);
    int*      endx      = beg + NG;

    // zero pooled|beg|endx (contiguous) and the esrc tail pad
    const int ZN = NG * HD + 2 * NG;
    zero_kernel<<<(ZN + 255) / 256, 256, 0, stream>>>((int*)pooled, ZN);
    zero_kernel<<<1, 64, 0, stream>>>(esrc + NE, 64);

    // CSR build: count -> scan -> (scatter fused w/ gemm1) -> rowptr -> fill
    bucket_count<<<NBL, 256, 0, stream>>>(col, batch, counts, beg, endx);
    block_reduce<<<NBS, 256, 0, stream>>>(counts, bsum);
    scan_bsum<<<1, 64, 0, stream>>>(bsum);
    block_scan<<<NBS, 256, 0, stream>>>(counts, bsum, counts_ex);
    gemm1_scatter<<<GEMM_BLOCKS + NBL, 256, 0, stream>>>(x, W1, h16, row, col,
                                                         counts_ex, packed);
    csr_rowptr<<<NBK, 256, 0, stream>>>(packed, counts_ex, rowptr, dinv);
    csr_fill<<<NBK, 256, 0, stream>>>(packed, counts_ex, rowptr, esrc);

    const int GB = NN / 4;  // gather blocks: 4 nodes (waves) each

    // Layer 1 aggregate: h16 -> A16
    gather_s<false><<<GB, 256, 0, stream>>>(h16, rowptr, esrc, dinv, b1, A16,
                                            batch, pooled);
    // Layer 2: relu(A16) -> h16 -> A16
    gemm64_f16<<<GEMM_BLOCKS, 256, 0, stream>>>(A16, W2, h16);
    gather_s<false><<<GB, 256, 0, stream>>>(h16, rowptr, esrc, dinv, b2, A16,
                                            batch, pooled);
    // Layer 3: relu(A16) -> h16 -> pooled (fused)
    gemm64_f16<<<GEMM_BLOCKS, 256, 0, stream>>>(A16, W3, h16);
    gather_s<true><<<GB, 256, 0, stream>>>(h16, rowptr, esrc, dinv, b3, nullptr,
                                           batch, pooled);

    final_kernel<<<NG, 64, 0, stream>>>(pooled, beg, endx, lin_W, lin_b, out);
}

// Round 12
// 269.257 us; speedup vs baseline: 1.3004x; 1.0075x over previous
//
#include <hip/hip_runtime.h>
#include <hip/hip_fp16.h>

// Problem constants (fixed by the reference file)
#define NN 50000     // nodes
#define NE 800000    // edges
#define HD 64        // feature dim (in and hidden)
#define NG 512       // graphs
#define NBK 196      // buckets: col >> 8, max 49999>>8 = 195
#define NBL 196      // edge blocks of 4096: ceil(NE/4096)
#define M_CNT (NBK * NBL)       // 38416 counts
#define NBS 151                 // scan blocks: ceil(M_CNT/256)
#define GEMM_BLOCKS 3125        // NN/16

// Math: out[c] = dinv[c]*(sum_src dinv[src]*h[src]) + dinv[c]^2*h[c] + b.
// Edge stream: src only (4 B/edge). In the gather, the edge list is
// WAVE-UNIFORM: node is forced uniform via readfirstlane so esrc[j] and
// dinv[src] compile to scalar (s_load) fetches — stream processing runs on
// the scalar pipe, vector pipes only do row gathers + FMA. No shuffles in
// the loop (R8/R10 divergence bug class structurally eliminated).

// ---------------------------------------------------------------------------
// zero pooled|beg|endx (n ints at p) + the 64-int esrc pad at q
__global__ void zero_kernel(int* __restrict__ p, int n, int* __restrict__ q) {
    int i = blockIdx.x * blockDim.x + threadIdx.x;
    if (i < n) p[i] = 0;
    if (i < 64) q[i] = 0;
}

// ---------------------------------------------------------------------------
// Pass A: per-(block,bucket) edge counts via LDS histogram (no global atomics)
// + graph node counts via sorted-batch boundary detection (atomic-free).
__global__ __launch_bounds__(256) void bucket_count(const int* __restrict__ col,
                                                    const int* __restrict__ batch,
                                                    int* __restrict__ counts,
                                                    int* __restrict__ beg,
                                                    int* __restrict__ endx) {
    __shared__ int hist[256];
    int tid = threadIdx.x, blk = blockIdx.x;
    hist[tid] = 0;
    __syncthreads();
    int base = blk * 4096;
#pragma unroll
    for (int k = 0; k < 16; ++k) {
        int e = base + k * 256 + tid;
        if (e < NE) atomicAdd(&hist[col[e] >> 8], 1);
    }
    // batch boundaries (batch is sorted); grid covers 50176 >= NN threads
    int t = blk * 256 + tid;
    if (t < NN) {
        int g = batch[t];
        if (t == 0 || batch[t - 1] != g) beg[g] = t;
        if (t == NN - 1 || batch[t + 1] != g) endx[g] = t + 1;
    }
    __syncthreads();
    if (tid < NBK) counts[tid * NBL + blk] = hist[tid];  // bucket-major
}

// ---- 3-stage exclusive scan over counts[M_CNT] ----------------------------
__global__ __launch_bounds__(256) void block_reduce(const int* __restrict__ src,
                                                    int* __restrict__ bsum) {
    __shared__ int ws[4];
    int tid = threadIdx.x, lane = tid & 63, wid = tid >> 6;
    int i = blockIdx.x * 256 + tid;
    int v = (i < M_CNT) ? src[i] : 0;
#pragma unroll
    for (int off = 32; off > 0; off >>= 1) v += __shfl_down(v, off, 64);
    if (lane == 0) ws[wid] = v;
    __syncthreads();
    if (tid == 0) bsum[blockIdx.x] = ws[0] + ws[1] + ws[2] + ws[3];
}

__global__ __launch_bounds__(64) void scan_bsum(int* __restrict__ bsum) {
    int lane = threadIdx.x;
    int carry = 0;
    for (int base = 0; base < NBS; base += 64) {
        int i = base + lane;
        int v = (i < NBS) ? bsum[i] : 0;
        int inc = v;
#pragma unroll
        for (int off = 1; off < 64; off <<= 1) {
            int t = __shfl_up(inc, off, 64);
            if (lane >= off) inc += t;
        }
        if (i < NBS) bsum[i] = carry + inc - v;  // exclusive
        carry += __shfl(inc, 63, 64);
    }
}

__global__ __launch_bounds__(256) void block_scan(const int* __restrict__ src,
                                                  const int* __restrict__ bsum,
                                                  int* __restrict__ dst) {
    __shared__ int ws[4];
    int tid = threadIdx.x, lane = tid & 63, wid = tid >> 6;
    int i = blockIdx.x * 256 + tid;
    int v = (i < M_CNT) ? src[i] : 0;
    int inc = v;
#pragma unroll
    for (int off = 1; off < 64; off <<= 1) {
        int t = __shfl_up(inc, off, 64);
        if (lane >= off) inc += t;
    }
    if (lane == 63) ws[wid] = inc;
    __syncthreads();
    int woff = 0;
    for (int k = 0; k < wid; ++k) woff += ws[k];
    if (i < M_CNT) dst[i] = bsum[blockIdx.x] + woff + inc - v;
}

// ---------------------------------------------------------------------------
// Fused: blocks [0,GEMM_BLOCKS) do h16 = x @ W1 (fp32 in, fp16 out);
// blocks [GEMM_BLOCKS, +NBL) scatter edges into bucket-ordered packed[].
__global__ __launch_bounds__(256) void gemm1_scatter(const float* __restrict__ x,
                                                     const float* __restrict__ W1,
                                                     __half* __restrict__ h16,
                                                     const int* __restrict__ row,
                                                     const int* __restrict__ col,
                                                     const int* __restrict__ counts_ex,
                                                     unsigned* __restrict__ packed) {
    if (blockIdx.x < GEMM_BLOCKS) {
        __shared__ float Ws[64][64];   // 16 KB
        __shared__ float Is[16][64];   // 4 KB
        int t = threadIdx.x;
        for (int i = t; i < 64 * 64; i += 256) Ws[i >> 6][i & 63] = W1[i];
        int row0 = blockIdx.x * 16;
        for (int i = t; i < 16 * 64; i += 256)
            Is[i >> 6][i & 63] = x[(row0 + (i >> 6)) * HD + (i & 63)];
        __syncthreads();
        int c = t & 63, r4 = t >> 6;
        float a0 = 0.f, a1 = 0.f, a2 = 0.f, a3 = 0.f;
#pragma unroll
        for (int k = 0; k < 64; ++k) {
            float w = Ws[k][c];
            a0 += Is[r4 + 0][k] * w;
            a1 += Is[r4 + 4][k] * w;
            a2 += Is[r4 + 8][k] * w;
            a3 += Is[r4 + 12][k] * w;
        }
        h16[(row0 + r4 + 0) * HD + c] = __float2half(a0);
        h16[(row0 + r4 + 4) * HD + c] = __float2half(a1);
        h16[(row0 + r4 + 8) * HD + c] = __float2half(a2);
        h16[(row0 + r4 + 12) * HD + c] = __float2half(a3);
    } else {
        __shared__ int cur[256];
        int tid = threadIdx.x, blk = blockIdx.x - GEMM_BLOCKS;
        cur[tid] = 0;
        __syncthreads();
        int base = blk * 4096;
#pragma unroll
        for (int k = 0; k < 16; ++k) {
            int e = base + k * 256 + tid;
            if (e < NE) {
                int c = col[e], r = row[e];
                int b = c >> 8;
                int lpos = atomicAdd(&cur[b], 1);
                int pos = counts_ex[b * NBL + blk] + lpos;
                packed[pos] = (unsigned)r | ((unsigned)(c & 255) << 16);
            }
        }
    }
}

// ---------------------------------------------------------------------------
// Fused CSR build: per bucket, histogram+scan -> rowptr/dinv (phase 1), then
// fill esrc via LDS cursors using the LDS-resident local rowptr (phase 2).
__global__ __launch_bounds__(256) void csr_build(const unsigned* __restrict__ packed,
                                                 const int* __restrict__ counts_ex,
                                                 int* __restrict__ rowptr,
                                                 float* __restrict__ dinv,
                                                 int* __restrict__ esrc) {
    __shared__ int hist[256];
    __shared__ int ws[4];
    __shared__ int lrp[256];
    int bkt = blockIdx.x, tid = threadIdx.x;
    int s = counts_ex[bkt * NBL];
    int e = (bkt == NBK - 1) ? NE : counts_ex[(bkt + 1) * NBL];
    hist[tid] = 0;
    __syncthreads();
    for (int j = s + tid; j < e; j += 256)
        atomicAdd(&hist[(packed[j] >> 16) & 255], 1);
    __syncthreads();
    int lane = tid & 63, wid = tid >> 6;
    int v = hist[tid], inc = v;
#pragma unroll
    for (int off = 1; off < 64; off <<= 1) {
        int t = __shfl_up(inc, off, 64);
        if (lane >= off) inc += t;
    }
    if (lane == 63) ws[wid] = inc;
    __syncthreads();
    int woff = 0;
    for (int k = 0; k < wid; ++k) woff += ws[k];
    int excl = s + woff + inc - v;               // exclusive scan
    int node = bkt * 256 + tid;
    if (node < NN) {
        rowptr[node] = excl;
        dinv[node] = rsqrtf((float)(v + 1));     // +1 self-loop
    }
    if (bkt == 0 && tid == 0) rowptr[NN] = NE;
    lrp[tid] = excl;
    hist[tid] = 0;                               // reuse as fill cursor
    __syncthreads();
    for (int j = s + tid; j < e; j += 256) {
        unsigned p = packed[j];
        int lc = (p >> 16) & 255;
        int slot = lrp[lc] + atomicAdd(&hist[lc], 1);
        esrc[slot] = (int)(p & 0xFFFF);          // NN < 65536
    }
}

// ---------------------------------------------------------------------------
// h16 = relu(in16) @ W   (layers 2,3)
__global__ __launch_bounds__(256) void gemm64_f16(const __half* __restrict__ in,
                                                  const float* __restrict__ W,
                                                  __half* __restrict__ out) {
    __shared__ float Ws[64][64];
    __shared__ float Is[16][64];
    int t = threadIdx.x;
    for (int i = t; i < 64 * 64; i += 256) Ws[i >> 6][i & 63] = W[i];
    int row0 = blockIdx.x * 16;
    const __half2* in2 = (const __half2*)(in + (size_t)row0 * HD);
    for (int i = t; i < 16 * 32; i += 256) {
        float2 v = __half22float2(in2[i]);
        int r = i >> 5, c2 = (i & 31) * 2;
        Is[r][c2]     = fmaxf(v.x, 0.f);
        Is[r][c2 + 1] = fmaxf(v.y, 0.f);
    }
    __syncthreads();
    int c = t & 63, r4 = t >> 6;
    float a0 = 0.f, a1 = 0.f, a2 = 0.f, a3 = 0.f;
#pragma unroll
    for (int k = 0; k < 64; ++k) {
        float w = Ws[k][c];
        a0 += Is[r4 + 0][k] * w;
        a1 += Is[r4 + 4][k] * w;
        a2 += Is[r4 + 8][k] * w;
        a3 += Is[r4 + 12][k] * w;
    }
    out[(row0 + r4 + 0) * HD + c] = __float2half(a0);
    out[(row0 + r4 + 4) * HD + c] = __float2half(a1);
    out[(row0 + r4 + 8) * HD + c] = __float2half(a2);
    out[(row0 + r4 + 12) * HD + c] = __float2half(a3);
}

// ---------------------------------------------------------------------------
// Scalar-stream CSR gather: ONE node per wave (node forced wave-uniform).
// esrc[j] / dinv[src] are uniform-address loads -> s_load (scalar pipe).
// Lane = 32*p + c: the wave processes 2 edges (p=0,1) x 32 half2 channels
// per step; unroll 4 -> 8 edges, 4 row-gather VMEM per wave step, no DS ops.
// Tail is uniform-predicated (no shuffles anywhere in the loop).
template <bool POOL>
__global__ __launch_bounds__(256) void gather_sc(const __half* __restrict__ hp,
                                                 const int* __restrict__ rowptr,
                                                 const int* __restrict__ esrc,
                                                 const float* __restrict__ dinv,
                                                 const float* __restrict__ b,
                                                 __half* __restrict__ out16,
                                                 const int* __restrict__ batch,
                                                 float* __restrict__ pooled) {
    int tid = threadIdx.x, lane = tid & 63, wid = tid >> 6;
    int p = lane >> 5, c = lane & 31;           // edge-of-pair, half2 channel
    int node = __builtin_amdgcn_readfirstlane(blockIdx.x * 4 + wid);
    const __half2* hv = (const __half2*)hp;
    int s = rowptr[node], e = rowptr[node + 1];     // scalar loads
    float2 acc = {0.f, 0.f};
    int j = s;
    for (; j + 8 <= e; j += 8) {
        int s0 = esrc[j + 0], s1 = esrc[j + 1], s2 = esrc[j + 2], s3 = esrc[j + 3];
        int s4 = esrc[j + 4], s5 = esrc[j + 5], s6 = esrc[j + 6], s7 = esrc[j + 7];
        float w0 = dinv[s0], w1 = dinv[s1], w2 = dinv[s2], w3 = dinv[s3];
        float w4 = dinv[s4], w5 = dinv[s5], w6 = dinv[s6], w7 = dinv[s7];
        int a0 = p ? s1 : s0;  float u0 = p ? w1 : w0;
        int a1 = p ? s3 : s2;  float u1 = p ? w3 : w2;
        int a2 = p ? s5 : s4;  float u2 = p ? w5 : w4;
        int a3 = p ? s7 : s6;  float u3 = p ? w7 : w6;
        float2 f0 = __half22float2(hv[a0 * 32 + c]);
        float2 f1 = __half22float2(hv[a1 * 32 + c]);
        float2 f2 = __half22float2(hv[a2 * 32 + c]);
        float2 f3 = __half22float2(hv[a3 * 32 + c]);
        acc.x += u0 * f0.x + u1 * f1.x + u2 * f2.x + u3 * f3.x;
        acc.y += u0 * f0.y + u1 * f1.y + u2 * f2.y + u3 * f3.y;
    }
    for (; j < e; j += 2) {                     // uniform-predicated tail
        int s0 = esrc[j];
        int s1 = (j + 1 < e) ? esrc[j + 1] : s0;   // esrc[e] in-bounds (pad)
        float w0 = dinv[s0];
        float w1 = (j + 1 < e) ? dinv[s1] : 0.f;
        int a = p ? s1 : s0;
        float u = p ? w1 : w0;
        float2 f = __half22float2(hv[a * 32 + c]);
        acc.x += u * f.x;
        acc.y += u * f.y;
    }
    // combine the two edge-pair partials (lane L ^ 32 holds same channel)
    acc.x += __shfl_xor(acc.x, 32, 64);
    acc.y += __shfl_xor(acc.y, 32, 64);
    if (p == 0) {
        float di = dinv[node];
        float2 self = __half22float2(hv[node * 32 + c]);
        float2 bb = ((const float2*)b)[c];
        float vx = di * acc.x + di * di * self.x + bb.x;
        float vy = di * acc.y + di * di * self.y + bb.y;
        if (POOL) {
            int g = batch[node];
            atomicAdd(&pooled[g * HD + 2 * c], vx);
            atomicAdd(&pooled[g * HD + 2 * c + 1], vy);
        } else {
            ((__half2*)out16)[node * 32 + c] = __floats2half2_rn(vx, vy);
        }
    }
}

// out[g] = (pooled[g,:]/max(cnt,1)) . lin_W + lin_b   — one wave per graph
__global__ __launch_bounds__(64) void final_kernel(const float* __restrict__ pooled,
                                                   const int* __restrict__ beg,
                                                   const int* __restrict__ endx,
                                                   const float* __restrict__ lin_W,
                                                   const float* __restrict__ lin_b,
                                                   float* __restrict__ out) {
    int g = blockIdx.x, d = threadIdx.x;
    float cnt = (float)(endx[g] - beg[g]);
    float v = pooled[g * HD + d] / fmaxf(cnt, 1.f) * lin_W[d];
#pragma unroll
    for (int off = 32; off > 0; off >>= 1) v += __shfl_down(v, off, 64);
    if (d == 0) out[g] = v + lin_b[0];
}

// ---------------------------------------------------------------------------
extern "C" void kernel_launch(void* const* d_in, const int* in_sizes, int n_in,
                              void* d_out, int out_size, void* d_ws, size_t ws_size,
                              hipStream_t stream) {
    const float* x     = (const float*)d_in[0];
    const float* W1    = (const float*)d_in[1];
    const float* b1    = (const float*)d_in[2];
    const float* W2    = (const float*)d_in[3];
    const float* b2    = (const float*)d_in[4];
    const float* W3    = (const float*)d_in[5];
    const float* b3    = (const float*)d_in[6];
    const float* lin_W = (const float*)d_in[7];
    const float* lin_b = (const float*)d_in[8];
    const int* edge_index = (const int*)d_in[9];   // [2, NE]: row then col
    const int* batch      = (const int*)d_in[10];
    const int* row = edge_index;
    const int* col = edge_index + NE;
    float* out = (float*)d_out;

    // workspace layout (4B units):
    // [h16 NN*HD half][A16 NN*HD half][esrc NE+64][packed NE]
    // [counts M][counts_ex M][rowptr NN+2][dinv NN][bsum 256]
    // [pooled NG*HD][beg NG][endx NG]
    __half*   h16       = (__half*)d_ws;
    __half*   A16       = h16 + (size_t)NN * HD;
    int*      esrc      = (int*)(A16 + (size_t)NN * HD);
    unsigned* packed    = (unsigned*)(esrc + NE + 64);
    int*      counts    = (int*)(packed + NE);
    int*      counts_ex = counts + M_CNT;
    int*      rowptr    = counts_ex + M_CNT;
    float*    dinv      = (float*)(rowptr + NN + 2);
    int*      bsum      = (int*)(dinv + NN);
    float*    pooled    = (float*)(bsum + 256);
    int*      beg       = (int*)(pooled + NG * HD);
    int*      endx      = beg + NG;

    // zero pooled|beg|endx (contiguous) + esrc tail pad (one launch)
    const int ZN = NG * HD + 2 * NG;
    zero_kernel<<<(ZN + 255) / 256, 256, 0, stream>>>((int*)pooled, ZN, esrc + NE);

    // CSR build: count -> scan -> (scatter fused w/ gemm1) -> fused rowptr+fill
    bucket_count<<<NBL, 256, 0, stream>>>(col, batch, counts, beg, endx);
    block_reduce<<<NBS, 256, 0, stream>>>(counts, bsum);
    scan_bsum<<<1, 64, 0, stream>>>(bsum);
    block_scan<<<NBS, 256, 0, stream>>>(counts, bsum, counts_ex);
    gemm1_scatter<<<GEMM_BLOCKS + NBL, 256, 0, stream>>>(x, W1, h16, row, col,
                                                         counts_ex, packed);
    csr_build<<<NBK, 256, 0, stream>>>(packed, counts_ex, rowptr, dinv, esrc);

    const int GB = NN / 4;  // gather blocks: 4 nodes (waves) each

    // Layer 1 aggregate: h16 -> A16
    gather_sc<false><<<GB, 256, 0, stream>>>(h16, rowptr, esrc, dinv, b1, A16,
                                             batch, pooled);
    // Layer 2: relu(A16) -> h16 -> A16
    gemm64_f16<<<GEMM_BLOCKS, 256, 0, stream>>>(A16, W2, h16);
    gather_sc<false><<<GB, 256, 0, stream>>>(h16, rowptr, esrc, dinv, b2, A16,
                                             batch, pooled);
    // Layer 3: relu(A16) -> h16 -> pooled (fused)
    gemm64_f16<<<GEMM_BLOCKS, 256, 0, stream>>>(A16, W3, h16);
    gather_sc<true><<<GB, 256, 0, stream>>>(h16, rowptr, esrc, dinv, b3, nullptr,
                                            batch, pooled);

    final_kernel<<<NG, 64, 0, stream>>>(pooled, beg, endx, lin_W, lin_b, out);
}